// Round 1
// baseline (82.083 us; speedup 1.0000x reference)
//
#include <hip/hip_runtime.h>
#include <math.h>

// FFM_69664369541798 — wave-per-row FFM scoring.
// B=262144 rows, 45 fp32 features, V=64 embedding dims (= wave size).
// Lane v owns embedding dim v. Row scalars broadcast via shfl/ballot.

constexpr int B_ROWS = 262144;
constexpr int NFEAT  = 45;
constexpr int RPW    = 16;   // rows per wave
constexpr int THREADS = 256;
constexpr int WPB    = THREADS / 64;

__global__ __launch_bounds__(THREADS) void ffm_kernel(
    const float* __restrict__ fv,
    const float* __restrict__ AU, const float* __restrict__ AI,
    const float* __restrict__ GU, const float* __restrict__ GI,
    const float* __restrict__ OU, const float* __restrict__ OI,
    const float* __restrict__ MU, const float* __restrict__ MI,
    const float* __restrict__ UU, const float* __restrict__ UI,
    const float* __restrict__ TU, const float* __restrict__ TI,
    const float* __restrict__ user_w, const float* __restrict__ item_w,
    const float* __restrict__ lin_w, const float* __restrict__ lin_b,
    float* __restrict__ out)
{
    const int lane    = threadIdx.x & 63;
    const int waveId  = blockIdx.x * WPB + (threadIdx.x >> 6);
    const int rowBase = waveId * RPW;

    // ---- per-wave invariant preloads (lane = dim v) ----
    const float au_w = AU[lane];
    const float ai_w = AI[lane];
    const float gu0  = GU[lane],      gu1 = GU[64 + lane];
    const float gi0  = GI[lane],      gi1 = GI[64 + lane];
    const float lw   = (lane >= 2 && lane < NFEAT) ? lin_w[lane - 2] : 0.0f;
    const float bias = lin_b[0];

    float sum_lin = lw;
    #pragma unroll
    for (int off = 32; off; off >>= 1) sum_lin += __shfl_xor(sum_lin, off);

    float myval = 0.0f;  // pre-sigmoid result parked on lane==r

    for (int r = 0; r < RPW; ++r) {
        const int row = rowBase + r;
        const float x = (lane < NFEAT) ? fv[row * NFEAT + lane] : 0.0f;

        const int   uid = (int)__shfl(x, 0);
        const int   iid = (int)__shfl(x, 1);
        const float age = __shfl(x, 2);
        const float g0  = __shfl(x, 3);
        const float g1  = __shfl(x, 4);

        const unsigned long long ball = __ballot(x != 0.0f);
        const unsigned occmask = (unsigned)((ball >> 5)  & 0x1FFFFFull); // 21 bits
        unsigned       movmask = (unsigned)((ball >> 26) & 0x7FFFFull);  // 19 bits

        const float au = age * au_w;
        const float ai = age * ai_w;
        const float gu = g0 * gu0 + g1 * gu1;
        const float gi = g0 * gi0 + g1 * gi1;

        float ou = 0.0f, oi = 0.0f;
        if (occmask) {
            const int j = __builtin_ctz(occmask);
            const float oval = __shfl(x, 5 + j);   // exactly 1.0 (one-hot), kept general
            ou = oval * OU[j * 64 + lane];
            oi = oval * OI[j * 64 + lane];
        }

        float mu = 0.0f, mi = 0.0f;
        while (movmask) {                          // wave-uniform loop, ~3.8 iters avg
            const int j = __builtin_ctz(movmask);
            movmask &= movmask - 1;
            const float mval = __shfl(x, 26 + j);  // exactly 1.0, kept general
            mu += mval * MU[j * 64 + lane];
            mi += mval * MI[j * 64 + lane];
        }

        const float uu  = UU[uid * 64 + lane];
        const float ui_ = UI[uid * 64 + lane];
        const float tu  = TU[iid * 64 + lane];
        const float ti  = TI[iid * 64 + lane];

        // cross regrouped: 15 pairwise dots -> 7 products per dim
        const float S    = mu + tu;
        const float part = (ai + gi + oi) * S
                         + au * (gu + ou + uu)
                         + gu * (ou + uu)
                         + ou * uu
                         + mu * ui_
                         + mi * ti
                         + ui_ * tu;

        // fuse cross- and dotfv-reductions: red = cross*sum_lin + dot(fv[2:],lin_w)
        float red = part * sum_lin + x * lw;
        #pragma unroll
        for (int off = 32; off; off >>= 1) red += __shfl_xor(red, off);

        const float val = user_w[uid] + item_w[iid] + bias + red;
        if (lane == r) myval = val;
    }

    if (lane < RPW) {
        const int row = rowBase + lane;
        out[row] = 1.0f / (1.0f + __expf(-myval));
    }
}

extern "C" void kernel_launch(void* const* d_in, const int* in_sizes, int n_in,
                              void* d_out, int out_size, void* d_ws, size_t ws_size,
                              hipStream_t stream) {
    const float* fv  = (const float*)d_in[0];
    const float* AU  = (const float*)d_in[1];
    const float* AI  = (const float*)d_in[2];
    const float* GU  = (const float*)d_in[3];
    const float* GI  = (const float*)d_in[4];
    const float* OU  = (const float*)d_in[5];
    const float* OI  = (const float*)d_in[6];
    const float* MU  = (const float*)d_in[7];
    const float* MI  = (const float*)d_in[8];
    const float* UU  = (const float*)d_in[9];
    const float* UI  = (const float*)d_in[10];
    const float* TU  = (const float*)d_in[11];
    const float* TI  = (const float*)d_in[12];
    const float* uw  = (const float*)d_in[13];
    const float* iw  = (const float*)d_in[14];
    const float* lw  = (const float*)d_in[15];
    const float* lb  = (const float*)d_in[16];
    float* out = (float*)d_out;

    const int waves  = B_ROWS / RPW;          // 16384
    const int blocks = waves / WPB;           // 4096
    ffm_kernel<<<blocks, THREADS, 0, stream>>>(
        fv, AU, AI, GU, GI, OU, OI, MU, MI, UU, UI, TU, TI, uw, iw, lw, lb, out);
}

// Round 2
// 68.980 us; speedup vs baseline: 1.1900x; 1.1900x over previous
//
#include <hip/hip_runtime.h>
#include <math.h>

// FFM_69664369541798 — wave-per-row FFM scoring, round 2.
// LDS-staged feature rows + 4-row ILP groups + uniform-LDS scalar broadcast.

constexpr int B_ROWS  = 262144;
constexpr int NFEAT   = 45;
constexpr int RPW     = 16;            // rows per wave
constexpr int THREADS = 256;
constexpr int WPB     = THREADS / 64;  // 4 waves per block
constexpr int FPW     = RPW * NFEAT;   // 720 floats staged per wave

__global__ __launch_bounds__(THREADS) void ffm_kernel(
    const float* __restrict__ fv,
    const float* __restrict__ AU, const float* __restrict__ AI,
    const float* __restrict__ GU, const float* __restrict__ GI,
    const float* __restrict__ OU, const float* __restrict__ OI,
    const float* __restrict__ MU, const float* __restrict__ MI,
    const float* __restrict__ UU, const float* __restrict__ UI,
    const float* __restrict__ TU, const float* __restrict__ TI,
    const float* __restrict__ user_w, const float* __restrict__ item_w,
    const float* __restrict__ lin_w, const float* __restrict__ lin_b,
    float* __restrict__ out)
{
    __shared__ __align__(16) float stage[WPB][FPW];

    const int lane    = threadIdx.x & 63;
    const int wid     = threadIdx.x >> 6;
    const int waveId  = blockIdx.x * WPB + wid;
    const int rowBase = waveId * RPW;

    // ---- stage 16 rows (2880 B) with 3 coalesced dwordx4 rounds ----
    {
        const float* src = fv + (size_t)rowBase * NFEAT;
        float*       dst = stage[wid];
        #pragma unroll
        for (int t = 0; t < 3; ++t) {
            const int idx = t * 64 + lane;            // dwordx4 slot
            if (idx < FPW / 4) {
                const float4 v = *reinterpret_cast<const float4*>(src + idx * 4);
                *reinterpret_cast<float4*>(dst + idx * 4) = v;
            }
        }
    }
    const float* __restrict__ S = stage[wid];

    // ---- per-wave invariant preloads (lane = dim v) ----
    const float au_w = AU[lane];
    const float ai_w = AI[lane];
    const float gu0  = GU[lane],      gu1 = GU[64 + lane];
    const float gi0  = GI[lane],      gi1 = GI[64 + lane];
    const float lw   = (lane >= 2 && lane < NFEAT) ? lin_w[lane - 2] : 0.0f;
    const float bias = lin_b[0];

    float sum_lin = lw;
    #pragma unroll
    for (int off = 32; off; off >>= 1) sum_lin += __shfl_xor(sum_lin, off);

    float myval = 0.0f;  // pre-sigmoid result parked on lane == row_local

    #pragma unroll
    for (int gq = 0; gq < RPW / 4; ++gq) {
        // phase A: per-row feature vector + wave-uniform scalars from LDS
        float   x[4], age[4], g0[4], g1[4];
        int     uid[4], iid[4];
        unsigned occm[4], movm[4];
        #pragma unroll
        for (int i = 0; i < 4; ++i) {
            const int r = gq * 4 + i;
            const float* rp = S + r * NFEAT;
            x[i]   = (lane < NFEAT) ? rp[lane] : 0.0f;
            uid[i] = (int)rp[0];
            iid[i] = (int)rp[1];
            age[i] = rp[2];
            g0[i]  = rp[3];
            g1[i]  = rp[4];
            const unsigned long long ball = __ballot(x[i] != 0.0f);
            occm[i] = (unsigned)((ball >> 5)  & 0x1FFFFFull);
            movm[i] = (unsigned)((ball >> 26) & 0x7FFFFull);
        }

        // phase B: issue all gathers for the 4 rows (independent, overlap)
        float uu[4], ui_[4], tu[4], ti[4], usw[4], itw[4];
        #pragma unroll
        for (int i = 0; i < 4; ++i) {
            uu[i]  = UU[uid[i] * 64 + lane];
            ui_[i] = UI[uid[i] * 64 + lane];
            tu[i]  = TU[iid[i] * 64 + lane];
            ti[i]  = TI[iid[i] * 64 + lane];
            usw[i] = user_w[uid[i]];
            itw[i] = item_w[iid[i]];
        }

        // phase C+D: compute partials, reduce (4 independent butterflies)
        #pragma unroll
        for (int i = 0; i < 4; ++i) {
            const float au = age[i] * au_w;
            const float ai = age[i] * ai_w;
            const float gu = g0[i] * gu0 + g1[i] * gu1;
            const float gi = g0[i] * gi0 + g1[i] * gi1;

            float ou = 0.0f, oi = 0.0f;
            if (occm[i]) {                    // wave-uniform; always taken
                const int j = __builtin_ctz(occm[i]);
                ou = OU[j * 64 + lane];       // one-hot value is exactly 1.0
                oi = OI[j * 64 + lane];
            }

            float mu = 0.0f, mi = 0.0f;
            unsigned m = movm[i];
            while (m) {                       // wave-uniform, ~3.8 iters avg
                const int j = __builtin_ctz(m);
                m &= m - 1;
                mu += MU[j * 64 + lane];      // binary feature: exactly 1.0
                mi += MI[j * 64 + lane];
            }

            // 15 pairwise dots regrouped into 7 products per dim
            const float part = (ai + gi + oi) * (mu + tu[i])
                             + au * (gu + ou + uu[i])
                             + gu * (ou + uu[i])
                             + ou * uu[i]
                             + mu * ui_[i]
                             + mi * ti[i]
                             + ui_[i] * tu[i];

            // fused reduction: cross*sum_lin + dot(fv[2:], lin_w)
            float red = part * sum_lin + x[i] * lw;
            #pragma unroll
            for (int off = 32; off; off >>= 1) red += __shfl_xor(red, off);

            const float val = usw[i] + itw[i] + bias + red;
            if (lane == gq * 4 + i) myval = val;
        }
    }

    if (lane < RPW) {
        out[rowBase + lane] = 1.0f / (1.0f + __expf(-myval));
    }
}

extern "C" void kernel_launch(void* const* d_in, const int* in_sizes, int n_in,
                              void* d_out, int out_size, void* d_ws, size_t ws_size,
                              hipStream_t stream) {
    const float* fv  = (const float*)d_in[0];
    const float* AU  = (const float*)d_in[1];
    const float* AI  = (const float*)d_in[2];
    const float* GU  = (const float*)d_in[3];
    const float* GI  = (const float*)d_in[4];
    const float* OU  = (const float*)d_in[5];
    const float* OI  = (const float*)d_in[6];
    const float* MU  = (const float*)d_in[7];
    const float* MI  = (const float*)d_in[8];
    const float* UU  = (const float*)d_in[9];
    const float* UI  = (const float*)d_in[10];
    const float* TU  = (const float*)d_in[11];
    const float* TI  = (const float*)d_in[12];
    const float* uw  = (const float*)d_in[13];
    const float* iw  = (const float*)d_in[14];
    const float* lw  = (const float*)d_in[15];
    const float* lb  = (const float*)d_in[16];
    float* out = (float*)d_out;

    const int waves  = B_ROWS / RPW;          // 16384
    const int blocks = waves / WPB;           // 4096
    ffm_kernel<<<blocks, THREADS, 0, stream>>>(
        fv, AU, AI, GU, GI, OU, OI, MU, MI, UU, UI, TU, TI, uw, iw, lw, lb, out);
}